// Round 6
// baseline (1376.256 us; speedup 1.0000x reference)
//
#include <hip/hip_runtime.h>
#include <hip/hip_bf16.h>

constexpr int TT = 4096;   // tokens
constexpr int HH = 2048;   // hidden
constexpr int II = 2048;   // intermediate
constexpr int EE = 16;     // experts
constexpr int KTOP = 4;    // top-k

typedef __attribute__((ext_vector_type(4))) float f4;
typedef __attribute__((ext_vector_type(8))) short s8;

__device__ __forceinline__ short f2bf(float f) {
    union { __hip_bfloat16 b; short s; } u;
    u.b = __float2bfloat16(f);
    return u.s;
}
__device__ __forceinline__ float bf2f(short s) {
    union { unsigned u; float f; } v;
    v.u = ((unsigned)(unsigned short)s) << 16;
    return v.f;
}

// async global->LDS, 16B per lane. LDS dest: wave-uniform base, HW adds lane*16.
__device__ __forceinline__ void g2l16(const void* g, void* l) {
    __builtin_amdgcn_global_load_lds(
        (const __attribute__((address_space(1))) void*)g,
        (__attribute__((address_space(3))) void*)l, 16, 0, 0);
}

// ---------------------------------------------------------------------------
// RMSNorm -> t_bf16; zeroes expert counters.
// ---------------------------------------------------------------------------
__global__ void k_rmsnorm(const float* __restrict__ x, const float* __restrict__ gamma,
                          short* __restrict__ t16, int* __restrict__ cnt) {
    const int row = blockIdx.x;
    const int tid = threadIdx.x;
    if (row == 0 && tid < EE) cnt[tid] = 0;
    const f4* xr = (const f4*)(x + (size_t)row * HH);
    f4 v0 = xr[tid * 2], v1 = xr[tid * 2 + 1];
    float ss = 0.f;
#pragma unroll
    for (int i = 0; i < 4; i++) { ss += v0[i] * v0[i]; ss += v1[i] * v1[i]; }
#pragma unroll
    for (int m = 32; m >= 1; m >>= 1) ss += __shfl_xor(ss, m);
    __shared__ float red[4];
    const int wid = tid >> 6, lane = tid & 63;
    if (lane == 0) red[wid] = ss;
    __syncthreads();
    const float tot = red[0] + red[1] + red[2] + red[3];
    const float rs = rsqrtf(tot * (1.f / HH) + 1e-6f);
    const f4* gr = (const f4*)gamma;
    f4 g0 = gr[tid * 2], g1 = gr[tid * 2 + 1];
    s8 o;
#pragma unroll
    for (int i = 0; i < 4; i++) {
        o[i]     = f2bf(v0[i] * rs * g0[i]);
        o[4 + i] = f2bf(v1[i] * rs * g1[i]);
    }
    *(s8*)(t16 + (size_t)row * HH + tid * 8) = o;
}

// ---------------------------------------------------------------------------
// Router: one wave per token, fp32 throughout (top-k tie safety).
// ---------------------------------------------------------------------------
__global__ void k_router(const float* __restrict__ x, const float* __restrict__ gamma,
                         const float* __restrict__ wg, const float* __restrict__ bg,
                         int* __restrict__ cnt, int* __restrict__ lst,
                         float* __restrict__ lwt) {
    const int lane = threadIdx.x & 63;
    const int tok = blockIdx.x * 4 + (threadIdx.x >> 6);
    const float* xr = x + (size_t)tok * HH;
    float t[32];
    float ss = 0.f;
#pragma unroll
    for (int j = 0; j < 32; j++) { float v = xr[lane + 64 * j]; t[j] = v; ss += v * v; }
#pragma unroll
    for (int m = 32; m >= 1; m >>= 1) ss += __shfl_xor(ss, m);
    const float rs = rsqrtf(ss * (1.f / HH) + 1e-6f);
#pragma unroll
    for (int j = 0; j < 32; j++) t[j] *= rs * gamma[lane + 64 * j];

    float logit[EE];
#pragma unroll
    for (int e = 0; e < EE; e++) {
        const float* wrow = wg + (size_t)e * HH;
        float a = 0.f;
#pragma unroll
        for (int j = 0; j < 32; j++) a += t[j] * wrow[lane + 64 * j];
#pragma unroll
        for (int m = 32; m >= 1; m >>= 1) a += __shfl_xor(a, m);
        logit[e] = a + bg[e];
    }
    unsigned chosen = 0u;
    int sel[KTOP]; float sv[KTOP];
#pragma unroll
    for (int k = 0; k < KTOP; k++) {
        float best = -1e30f; int bi = 0;
#pragma unroll
        for (int e = 0; e < EE; e++) {
            bool take = (!((chosen >> e) & 1u)) && (logit[e] > best);
            if (take) { best = logit[e]; bi = e; }
        }
        chosen |= 1u << bi; sel[k] = bi; sv[k] = best;
    }
    const float lmax = sv[0];
    float s = 0.f;
#pragma unroll
    for (int k = 0; k < KTOP; k++) { sv[k] = expf(sv[k] - lmax); s += sv[k]; }
    const float inv = 1.f / s;
    if (lane == 0) {
#pragma unroll
        for (int k = 0; k < KTOP; k++) {
            int e = sel[k];
            int p = atomicAdd(&cnt[e], 1);
            lst[e * TT + p] = tok * KTOP + k;
            lwt[e * TT + p] = sv[k] * inv;
        }
    }
}

// ---------------------------------------------------------------------------
// fp32 -> bf16 weight convert (streaming, 8 elems/thread)
// ---------------------------------------------------------------------------
__global__ void k_convert(const float* __restrict__ src, short* __restrict__ dst) {
    size_t i = (size_t)blockIdx.x * 256 + threadIdx.x;
    f4 a = ((const f4*)src)[i * 2];
    f4 b = ((const f4*)src)[i * 2 + 1];
    s8 o;
#pragma unroll
    for (int j = 0; j < 4; j++) { o[j] = f2bf(a[j]); o[4 + j] = f2bf(b[j]); }
    ((s8*)dst)[i] = o;
}

// ---------------------------------------------------------------------------
// Grouped GEMM, 256x256 tile, BK=64, 8 waves, dbuf LDS (128 KiB),
// global_load_lds w16 with pre-swizzled source (T2), counted vmcnt(8)
// 1-deep prefetch (T4), setprio (T5).
//
// T1 (this round's change): 1-D grid + XCD-chunked, M-fastest decode.
//   lin -> work = (lin>>3) + (lin&7)*(nwg/8)   (8 XCDs, nwg%8==0)
//   work -> mt = work&15, nt = (work>>4)&7, e = work>>7
// Each XCD sweeps all M-tiles of one (nt,e) weight panel (1 MB, L2-resident)
// before advancing; each XCD touches only 2 experts' weights.
//
// OP: 0 = gate (write h1 raw), 1 = up (silu(gate)*up -> h1), 2 = down (*wgt).
// ---------------------------------------------------------------------------
template<int OP>
__global__ __launch_bounds__(512, 2) void k_gemm256(
        const short* __restrict__ Abase, const short* __restrict__ Wb,
        short* __restrict__ Out, const int* __restrict__ cnt,
        const int* __restrict__ lst, const float* __restrict__ lwt) {
    // ---- T1 decode: 2048 blocks = 16 mt x 8 nt x 16 e ----
    const int lin = blockIdx.x;
    const int work = (lin >> 3) + (lin & 7) * 256;   // nwg/8 = 256
    const int mt = work & 15;
    const int nt = (work >> 4) & 7;
    const int e  = work >> 7;

    const int Me = cnt[e];
    const int m0 = mt * 256;
    if (m0 >= Me) return;
    const int n0 = nt * 256;
    const short* we = Wb + (size_t)e * 2048 * 2048;

    __shared__ short lA[2][256 * 64];
    __shared__ short lB[2][256 * 64];
    __shared__ int s_tok[256];
    __shared__ float s_wgt[256];

    const int tid = threadIdx.x;
    if (tid < 256) {
        bool v = (m0 + tid < Me);
        s_tok[tid] = v ? lst[e * TT + m0 + tid] : 0;
        if (OP == 2) s_wgt[tid] = v ? lwt[e * TT + m0 + tid] : 0.f;
    }
    __syncthreads();

    const int lane = tid & 63, w = tid >> 6;
    const int wr = w >> 2, wc = w & 3;     // 2 x 4 wave grid; wave owns 128x64

    // staging: issue i covers rows i*64+(tid>>3), chunk tid&7 (x8 bf16);
    // pre-swizzled source chunk c ^ (row&7) => linear LDS holds swizzled data.
    const short* ga[4]; const short* gb[4];
    {
        const int rsub = tid >> 3;                       // 0..63
        const int csw = ((tid & 7) ^ (rsub & 7)) * 8;
#pragma unroll
        for (int i = 0; i < 4; i++) {
            int row = i * 64 + rsub;
            int pk = s_tok[row];
            int arow = (OP == 2) ? pk : (pk >> 2);
            ga[i] = Abase + (size_t)arow * 2048 + csw;
            gb[i] = we + (size_t)(n0 + row) * 2048 + csw;
        }
    }

    f4 acc[8][4];
    const f4 zero = {0.f, 0.f, 0.f, 0.f};
#pragma unroll
    for (int i = 0; i < 8; i++)
#pragma unroll
        for (int j = 0; j < 4; j++) acc[i][j] = zero;

#define STAGE(db, kt)                                                          \
    {                                                                          \
        _Pragma("unroll")                                                      \
        for (int i = 0; i < 4; i++)                                            \
            g2l16(ga[i] + (kt) * 64, (char*)lA[db] + i * 8192 + w * 1024);     \
        _Pragma("unroll")                                                      \
        for (int i = 0; i < 4; i++)                                            \
            g2l16(gb[i] + (kt) * 64, (char*)lB[db] + i * 8192 + w * 1024);     \
    }

    STAGE(0, 0);
    const int nkt = 2048 / 64;   // 32
    for (int kt = 0; kt < nkt; ++kt) {
        const int db = kt & 1;
        if (kt + 1 < nkt) {
            STAGE(db ^ 1, kt + 1);
            asm volatile("s_waitcnt vmcnt(8)" ::: "memory");   // tile kt landed
        } else {
            asm volatile("s_waitcnt vmcnt(0)" ::: "memory");
        }
        __builtin_amdgcn_s_barrier();          // all waves: tile kt visible
        asm volatile("" ::: "memory");
#pragma unroll
        for (int kk = 0; kk < 2; ++kk) {
            s8 af[8], bf[4];
#pragma unroll
            for (int mf = 0; mf < 8; mf++) {
                int r = wr * 128 + mf * 16 + (lane & 15);
                int off = (kk * 64 + ((lane >> 4) << 4)) ^ ((r & 7) << 4);
                af[mf] = *(const s8*)((const char*)lA[db] + r * 128 + off);
            }
#pragma unroll
            for (int nf = 0; nf < 4; nf++) {
                int r = wc * 64 + nf * 16 + (lane & 15);
                int off = (kk * 64 + ((lane >> 4) << 4)) ^ ((r & 7) << 4);
                bf[nf] = *(const s8*)((const char*)lB[db] + r * 128 + off);
            }
            __builtin_amdgcn_s_setprio(1);
#pragma unroll
            for (int mf = 0; mf < 8; mf++)
#pragma unroll
                for (int nf = 0; nf < 4; nf++)
                    acc[mf][nf] = __builtin_amdgcn_mfma_f32_16x16x32_bf16(
                        af[mf], bf[nf], acc[mf][nf], 0, 0, 0);
            __builtin_amdgcn_s_setprio(0);
        }
        asm volatile("" ::: "memory");
        __builtin_amdgcn_s_barrier();          // all reads of buf[db] retired
        asm volatile("" ::: "memory");
    }
#undef STAGE

    // epilogue: C/D layout col=lane&15, row=(lane>>4)*4+reg
#pragma unroll
    for (int mf = 0; mf < 8; mf++) {
#pragma unroll
        for (int j = 0; j < 4; j++) {
            int rl = wr * 128 + mf * 16 + ((lane >> 4) << 2) + j;
            if (m0 + rl < Me) {
                int pk = s_tok[rl];
                size_t orow = (size_t)pk * 2048;
#pragma unroll
                for (int nf = 0; nf < 4; nf++) {
                    int ncol = n0 + wc * 64 + nf * 16 + (lane & 15);
                    if (OP == 0) {
                        Out[orow + ncol] = f2bf(acc[mf][nf][j]);
                    } else if (OP == 1) {
                        float u = acc[mf][nf][j];
                        float g = bf2f(Out[orow + ncol]);
                        float sg = g / (1.f + expf(-g));
                        Out[orow + ncol] = f2bf(sg * u);
                    } else {
                        Out[orow + ncol] = f2bf(acc[mf][nf][j] * s_wgt[rl]);
                    }
                }
            }
        }
    }
}

// ---------------------------------------------------------------------------
// Final: out = x + sum_k buf2[token*4+k]  (buf2 bf16)
// ---------------------------------------------------------------------------
__global__ void k_final(const float* __restrict__ x, const short* __restrict__ buf2,
                        float* __restrict__ out) {
    size_t i8 = (size_t)blockIdx.x * 256 + threadIdx.x;  // 8-elem chunk
    size_t tok = i8 / (HH / 8);
    size_t c8 = i8 % (HH / 8);
    const f4* xp = (const f4*)x + i8 * 2;
    f4 r0 = xp[0], r1 = xp[1];
#pragma unroll
    for (int k = 0; k < KTOP; k++) {
        s8 b = ((const s8*)buf2)[(tok * KTOP + k) * (HH / 8) + c8];
#pragma unroll
        for (int j = 0; j < 4; j++) { r0[j] += bf2f(b[j]); r1[j] += bf2f(b[4 + j]); }
    }
    ((f4*)out)[i8 * 2] = r0;
    ((f4*)out)[i8 * 2 + 1] = r1;
}

// ---------------------------------------------------------------------------
extern "C" void kernel_launch(void* const* d_in, const int* in_sizes, int n_in,
                              void* d_out, int out_size, void* d_ws, size_t ws_size,
                              hipStream_t stream) {
    const float* x     = (const float*)d_in[0];
    const float* gamma = (const float*)d_in[1];
    const float* wg    = (const float*)d_in[2];
    const float* bg    = (const float*)d_in[3];
    const float* w1    = (const float*)d_in[4];
    const float* w3    = (const float*)d_in[5];
    const float* w2    = (const float*)d_in[6];
    float* out = (float*)d_out;

    char* ws = (char*)d_ws;
    size_t off = 0;
    short* t16  = (short*)(ws + off); off += (size_t)TT * HH * 2;          // 16 MB
    short* h1   = (short*)(ws + off); off += (size_t)TT * KTOP * II * 2;   // 64 MB
    short* buf2 = (short*)(ws + off); off += (size_t)TT * KTOP * HH * 2;   // 64 MB
    short* wbuf = (short*)(ws + off); off += (size_t)EE * II * HH * 2;     // 128 MB
    int* cnt    = (int*)(ws + off); off += 256;
    int* lst    = (int*)(ws + off); off += (size_t)EE * TT * 4;
    float* lwt  = (float*)(ws + off); off += (size_t)EE * TT * 4;

    const int convBlocks = (EE * II * HH / 8) / 256;   // 32768

    k_rmsnorm<<<TT, 256, 0, stream>>>(x, gamma, t16, cnt);
    k_router<<<TT / 4, 256, 0, stream>>>(x, gamma, wg, bg, cnt, lst, lwt);

    const int gemmBlocks = 16 * 8 * EE;   // 2048 (mt x nt x e), both shapes

    k_convert<<<convBlocks, 256, 0, stream>>>(w1, wbuf);
    k_gemm256<0><<<gemmBlocks, 512, 0, stream>>>(t16, wbuf, h1, cnt, lst, lwt);
    k_convert<<<convBlocks, 256, 0, stream>>>(w3, wbuf);
    k_gemm256<1><<<gemmBlocks, 512, 0, stream>>>(t16, wbuf, h1, cnt, lst, lwt);

    k_convert<<<convBlocks, 256, 0, stream>>>(w2, wbuf);
    k_gemm256<2><<<gemmBlocks, 512, 0, stream>>>(h1, wbuf, buf2, cnt, lst, lwt);

    k_final<<<(TT * HH / 8) / 256, 256, 0, stream>>>(x, buf2, out);
}

// Round 7
// 922.987 us; speedup vs baseline: 1.4911x; 1.4911x over previous
//
#include <hip/hip_runtime.h>
#include <hip/hip_bf16.h>

constexpr int TT = 4096;   // tokens
constexpr int HH = 2048;   // hidden
constexpr int II = 2048;   // intermediate
constexpr int EE = 16;     // experts
constexpr int KTOP = 4;    // top-k

typedef __attribute__((ext_vector_type(4))) float f4;
typedef __attribute__((ext_vector_type(8))) short s8;

__device__ __forceinline__ short f2bf(float f) {
    union { __hip_bfloat16 b; short s; } u;
    u.b = __float2bfloat16(f);
    return u.s;
}
__device__ __forceinline__ float bf2f(short s) {
    union { unsigned u; float f; } v;
    v.u = ((unsigned)(unsigned short)s) << 16;
    return v.f;
}

// ---------------------------------------------------------------------------
// RMSNorm -> t_bf16; zeroes expert counters.
// ---------------------------------------------------------------------------
__global__ void k_rmsnorm(const float* __restrict__ x, const float* __restrict__ gamma,
                          short* __restrict__ t16, int* __restrict__ cnt) {
    const int row = blockIdx.x;
    const int tid = threadIdx.x;
    if (row == 0 && tid < EE) cnt[tid] = 0;
    const f4* xr = (const f4*)(x + (size_t)row * HH);
    f4 v0 = xr[tid * 2], v1 = xr[tid * 2 + 1];
    float ss = 0.f;
#pragma unroll
    for (int i = 0; i < 4; i++) { ss += v0[i] * v0[i]; ss += v1[i] * v1[i]; }
#pragma unroll
    for (int m = 32; m >= 1; m >>= 1) ss += __shfl_xor(ss, m);
    __shared__ float red[4];
    const int wid = tid >> 6, lane = tid & 63;
    if (lane == 0) red[wid] = ss;
    __syncthreads();
    const float tot = red[0] + red[1] + red[2] + red[3];
    const float rs = rsqrtf(tot * (1.f / HH) + 1e-6f);
    const f4* gr = (const f4*)gamma;
    f4 g0 = gr[tid * 2], g1 = gr[tid * 2 + 1];
    s8 o;
#pragma unroll
    for (int i = 0; i < 4; i++) {
        o[i]     = f2bf(v0[i] * rs * g0[i]);
        o[4 + i] = f2bf(v1[i] * rs * g1[i]);
    }
    *(s8*)(t16 + (size_t)row * HH + tid * 8) = o;
}

// ---------------------------------------------------------------------------
// Router: one wave per token, fp32 throughout (top-k tie safety).
// ---------------------------------------------------------------------------
__global__ void k_router(const float* __restrict__ x, const float* __restrict__ gamma,
                         const float* __restrict__ wg, const float* __restrict__ bg,
                         int* __restrict__ cnt, int* __restrict__ lst,
                         float* __restrict__ lwt) {
    const int lane = threadIdx.x & 63;
    const int tok = blockIdx.x * 4 + (threadIdx.x >> 6);
    const float* xr = x + (size_t)tok * HH;
    float t[32];
    float ss = 0.f;
#pragma unroll
    for (int j = 0; j < 32; j++) { float v = xr[lane + 64 * j]; t[j] = v; ss += v * v; }
#pragma unroll
    for (int m = 32; m >= 1; m >>= 1) ss += __shfl_xor(ss, m);
    const float rs = rsqrtf(ss * (1.f / HH) + 1e-6f);
#pragma unroll
    for (int j = 0; j < 32; j++) t[j] *= rs * gamma[lane + 64 * j];

    float logit[EE];
#pragma unroll
    for (int e = 0; e < EE; e++) {
        const float* wrow = wg + (size_t)e * HH;
        float a = 0.f;
#pragma unroll
        for (int j = 0; j < 32; j++) a += t[j] * wrow[lane + 64 * j];
#pragma unroll
        for (int m = 32; m >= 1; m >>= 1) a += __shfl_xor(a, m);
        logit[e] = a + bg[e];
    }
    unsigned chosen = 0u;
    int sel[KTOP]; float sv[KTOP];
#pragma unroll
    for (int k = 0; k < KTOP; k++) {
        float best = -1e30f; int bi = 0;
#pragma unroll
        for (int e = 0; e < EE; e++) {
            bool take = (!((chosen >> e) & 1u)) && (logit[e] > best);
            if (take) { best = logit[e]; bi = e; }
        }
        chosen |= 1u << bi; sel[k] = bi; sv[k] = best;
    }
    const float lmax = sv[0];
    float s = 0.f;
#pragma unroll
    for (int k = 0; k < KTOP; k++) { sv[k] = expf(sv[k] - lmax); s += sv[k]; }
    const float inv = 1.f / s;
    if (lane == 0) {
#pragma unroll
        for (int k = 0; k < KTOP; k++) {
            int e = sel[k];
            int p = atomicAdd(&cnt[e], 1);
            lst[e * TT + p] = tok * KTOP + k;
            lwt[e * TT + p] = sv[k] * inv;
        }
    }
}

// ---------------------------------------------------------------------------
// FUSED gate+up grouped GEMM: h[pk] = silu(t@w1e^T) * (t@w3e^T).
// 128x128 output tile (both halves), BK=64, 4 waves. A staged ONCE per block,
// B1 (w1) and B2 (w3) fp32->bf16 reg-staged. XOR-swizzled ds_write/ds_read
// (round-1-verified geometry, 0 bank conflicts). Epilogue: silu fused, single
// h write, no global RMW.
// ---------------------------------------------------------------------------
__global__ __launch_bounds__(256, 2) void k_gemm_ffn_fused(
        const short* __restrict__ t16, const float* __restrict__ w1,
        const float* __restrict__ w3, short* __restrict__ h,
        const int* __restrict__ cnt, const int* __restrict__ lst) {
    const int e = blockIdx.z;
    const int Me = cnt[e];
    const int m0 = blockIdx.y * 128;
    if (m0 >= Me) return;
    const int n0 = blockIdx.x * 128;
    const float* we1 = w1 + (size_t)e * II * HH;   // [N=I][K=H] row-major
    const float* we3 = w3 + (size_t)e * II * HH;

    __shared__ char lA[16384];
    __shared__ char lB1[16384];
    __shared__ char lB2[16384];
    __shared__ int s_tok[128];

    const int tid = threadIdx.x;
    if (tid < 128) s_tok[tid] = (m0 + tid < Me) ? lst[e * TT + m0 + tid] : 0;
    __syncthreads();

    const int lane = tid & 63, wid = tid >> 6;
    const int wr = wid >> 1, wc = wid & 1;

    f4 acc1[4][4], acc2[4][4];
    const f4 zero = {0.f, 0.f, 0.f, 0.f};
#pragma unroll
    for (int i = 0; i < 4; i++)
#pragma unroll
        for (int j = 0; j < 4; j++) { acc1[i][j] = zero; acc2[i][j] = zero; }

    // staging geometry (round-1-verified): thread covers rows rbase+32j at
    // k-chunk kc (8 elems); lb0 XOR-swizzled by row&7.
    const int rbase = tid >> 3;
    const int kc = (tid & 7) * 8;
    const int lb0 = rbase * 128 + ((kc * 2) ^ ((rbase & 7) << 4));
    int tokrow[4];
#pragma unroll
    for (int j = 0; j < 4; j++) tokrow[j] = s_tok[rbase + 32 * j] >> 2;

    for (int kt = 0; kt < HH / 64; ++kt) {
        __syncthreads();
        // stage A (gathered bf16 rows)
#pragma unroll
        for (int j = 0; j < 4; j++) {
            s8 av = *(const s8*)(t16 + (size_t)tokrow[j] * HH + kt * 64 + kc);
            *(s8*)(lA + lb0 + 4096 * j) = av;
        }
        // stage B1, B2 (fp32 -> bf16)
#pragma unroll
        for (int j = 0; j < 4; j++) {
            size_t roff = (size_t)(n0 + rbase + 32 * j) * HH + kt * 64 + kc;
            {
                f4 b0 = *(const f4*)(we1 + roff);
                f4 b1 = *(const f4*)(we1 + roff + 4);
                s8 bv;
#pragma unroll
                for (int i = 0; i < 4; i++) { bv[i] = f2bf(b0[i]); bv[4 + i] = f2bf(b1[i]); }
                *(s8*)(lB1 + lb0 + 4096 * j) = bv;
            }
            {
                f4 b0 = *(const f4*)(we3 + roff);
                f4 b1 = *(const f4*)(we3 + roff + 4);
                s8 bv;
#pragma unroll
                for (int i = 0; i < 4; i++) { bv[i] = f2bf(b0[i]); bv[4 + i] = f2bf(b1[i]); }
                *(s8*)(lB2 + lb0 + 4096 * j) = bv;
            }
        }
        __syncthreads();
#pragma unroll
        for (int kk = 0; kk < 2; ++kk) {
            s8 af[4], b1v[4], b2v[4];
#pragma unroll
            for (int mf = 0; mf < 4; mf++) {
                int r = wr * 64 + mf * 16 + (lane & 15);
                int byte = r * 128 + (((kk * 64) + ((lane >> 4) << 4)) ^ ((r & 7) << 4));
                af[mf] = *(const s8*)(lA + byte);
            }
#pragma unroll
            for (int nf = 0; nf < 4; nf++) {
                int r = wc * 64 + nf * 16 + (lane & 15);
                int byte = r * 128 + (((kk * 64) + ((lane >> 4) << 4)) ^ ((r & 7) << 4));
                b1v[nf] = *(const s8*)(lB1 + byte);
                b2v[nf] = *(const s8*)(lB2 + byte);
            }
#pragma unroll
            for (int mf = 0; mf < 4; mf++)
#pragma unroll
                for (int nf = 0; nf < 4; nf++) {
                    acc1[mf][nf] = __builtin_amdgcn_mfma_f32_16x16x32_bf16(
                        af[mf], b1v[nf], acc1[mf][nf], 0, 0, 0);
                    acc2[mf][nf] = __builtin_amdgcn_mfma_f32_16x16x32_bf16(
                        af[mf], b2v[nf], acc2[mf][nf], 0, 0, 0);
                }
        }
    }
    // epilogue: h = silu(gate) * up.  C/D layout col=lane&15, row=(lane>>4)*4+reg
#pragma unroll
    for (int mf = 0; mf < 4; mf++) {
#pragma unroll
        for (int j = 0; j < 4; j++) {
            int rl = wr * 64 + mf * 16 + ((lane >> 4) << 2) + j;
            if (m0 + rl < Me) {
                size_t orow = (size_t)s_tok[rl] * II;
#pragma unroll
                for (int nf = 0; nf < 4; nf++) {
                    int ncol = n0 + wc * 64 + nf * 16 + (lane & 15);
                    float g = acc1[mf][nf][j];
                    float u = acc2[mf][nf][j];
                    float sg = g / (1.f + expf(-g));
                    h[orow + ncol] = f2bf(sg * u);
                }
            }
        }
    }
}

// ---------------------------------------------------------------------------
// Grouped GEMM (down): buf2[pk] = (h[pk] @ W2[e]^T) * weight, bf16 out.
// Round-1-verified structure (reg-staged fp32 B, XOR swizzle).
// ---------------------------------------------------------------------------
__global__ __launch_bounds__(256) void k_gemm_down(
        const short* __restrict__ h, const float* __restrict__ w2,
        short* __restrict__ buf2, const int* __restrict__ cnt,
        const int* __restrict__ lst, const float* __restrict__ lwt) {
    const int e = blockIdx.z;
    const int Me = cnt[e];
    const int m0 = blockIdx.y * 128;
    if (m0 >= Me) return;
    const int n0 = blockIdx.x * 128;
    const float* we = w2 + (size_t)e * HH * II;  // [N=H][K=I] row-major

    __shared__ char lA[16384];
    __shared__ char lB[16384];
    __shared__ int s_tok[128];
    __shared__ float s_wgt[128];

    const int tid = threadIdx.x;
    if (tid < 128) {
        bool v = (m0 + tid < Me);
        s_tok[tid] = v ? lst[e * TT + m0 + tid] : 0;
        s_wgt[tid] = v ? lwt[e * TT + m0 + tid] : 0.f;
    }
    __syncthreads();

    const int lane = tid & 63, wid = tid >> 6;
    const int wr = wid >> 1, wc = wid & 1;

    f4 acc[4][4];
    const f4 zero = {0.f, 0.f, 0.f, 0.f};
#pragma unroll
    for (int i = 0; i < 4; i++)
#pragma unroll
        for (int j = 0; j < 4; j++) acc[i][j] = zero;

    const int rbase = tid >> 3;
    const int kc = (tid & 7) * 8;
    const int lb0 = rbase * 128 + ((kc * 2) ^ ((rbase & 7) << 4));
    int arow[4];
#pragma unroll
    for (int j = 0; j < 4; j++) arow[j] = s_tok[rbase + 32 * j];  // pk is the h-row

    for (int kt = 0; kt < II / 64; ++kt) {
        __syncthreads();
#pragma unroll
        for (int j = 0; j < 4; j++) {
            s8 av = *(const s8*)(h + (size_t)arow[j] * II + kt * 64 + kc);
            *(s8*)(lA + lb0 + 4096 * j) = av;
        }
#pragma unroll
        for (int j = 0; j < 4; j++) {
            const float* gp = we + (size_t)(n0 + rbase + 32 * j) * II + kt * 64 + kc;
            f4 b0 = *(const f4*)gp;
            f4 b1 = *(const f4*)(gp + 4);
            s8 bv;
#pragma unroll
            for (int i = 0; i < 4; i++) { bv[i] = f2bf(b0[i]); bv[4 + i] = f2bf(b1[i]); }
            *(s8*)(lB + lb0 + 4096 * j) = bv;
        }
        __syncthreads();
#pragma unroll
        for (int kk = 0; kk < 2; ++kk) {
            s8 af[4], bfr[4];
#pragma unroll
            for (int mf = 0; mf < 4; mf++) {
                int r = wr * 64 + mf * 16 + (lane & 15);
                int byte = r * 128 + (((kk * 64) + ((lane >> 4) << 4)) ^ ((r & 7) << 4));
                af[mf] = *(const s8*)(lA + byte);
            }
#pragma unroll
            for (int nf = 0; nf < 4; nf++) {
                int r = wc * 64 + nf * 16 + (lane & 15);
                int byte = r * 128 + (((kk * 64) + ((lane >> 4) << 4)) ^ ((r & 7) << 4));
                bfr[nf] = *(const s8*)(lB + byte);
            }
#pragma unroll
            for (int mf = 0; mf < 4; mf++)
#pragma unroll
                for (int nf = 0; nf < 4; nf++)
                    acc[mf][nf] = __builtin_amdgcn_mfma_f32_16x16x32_bf16(
                        af[mf], bfr[nf], acc[mf][nf], 0, 0, 0);
        }
    }
#pragma unroll
    for (int mf = 0; mf < 4; mf++) {
#pragma unroll
        for (int j = 0; j < 4; j++) {
            int rl = wr * 64 + mf * 16 + ((lane >> 4) << 2) + j;
            if (m0 + rl < Me) {
                size_t orow = (size_t)s_tok[rl] * HH;
                float wgt = s_wgt[rl];
#pragma unroll
                for (int nf = 0; nf < 4; nf++) {
                    int ncol = n0 + wc * 64 + nf * 16 + (lane & 15);
                    buf2[orow + ncol] = f2bf(acc[mf][nf][j] * wgt);
                }
            }
        }
    }
}

// ---------------------------------------------------------------------------
// Final: out = x + sum_k buf2[token*4+k]  (buf2 bf16)
// ---------------------------------------------------------------------------
__global__ void k_final(const float* __restrict__ x, const short* __restrict__ buf2,
                        float* __restrict__ out) {
    size_t i8 = (size_t)blockIdx.x * 256 + threadIdx.x;  // 8-elem chunk
    size_t tok = i8 / (HH / 8);
    size_t c8 = i8 % (HH / 8);
    const f4* xp = (const f4*)x + i8 * 2;
    f4 r0 = xp[0], r1 = xp[1];
#pragma unroll
    for (int k = 0; k < KTOP; k++) {
        s8 b = ((const s8*)buf2)[(tok * KTOP + k) * (HH / 8) + c8];
#pragma unroll
        for (int j = 0; j < 4; j++) { r0[j] += bf2f(b[j]); r1[j] += bf2f(b[4 + j]); }
    }
    ((f4*)out)[i8 * 2] = r0;
    ((f4*)out)[i8 * 2 + 1] = r1;
}

// ---------------------------------------------------------------------------
extern "C" void kernel_launch(void* const* d_in, const int* in_sizes, int n_in,
                              void* d_out, int out_size, void* d_ws, size_t ws_size,
                              hipStream_t stream) {
    const float* x     = (const float*)d_in[0];
    const float* gamma = (const float*)d_in[1];
    const float* wg    = (const float*)d_in[2];
    const float* bg    = (const float*)d_in[3];
    const float* w1    = (const float*)d_in[4];
    const float* w3    = (const float*)d_in[5];
    const float* w2    = (const float*)d_in[6];
    float* out = (float*)d_out;

    char* ws = (char*)d_ws;
    size_t off = 0;
    short* t16  = (short*)(ws + off); off += (size_t)TT * HH * 2;          // 16 MB
    short* h1   = (short*)(ws + off); off += (size_t)TT * KTOP * II * 2;   // 64 MB
    short* buf2 = (short*)(ws + off); off += (size_t)TT * KTOP * HH * 2;   // 64 MB
    int* cnt    = (int*)(ws + off); off += 256;
    int* lst    = (int*)(ws + off); off += (size_t)EE * TT * 4;
    float* lwt  = (float*)(ws + off); off += (size_t)EE * TT * 4;

    k_rmsnorm<<<TT, 256, 0, stream>>>(x, gamma, t16, cnt);
    k_router<<<TT / 4, 256, 0, stream>>>(x, gamma, wg, bg, cnt, lst, lwt);

    dim3 g1(II / 128, TT / 128, EE);
    k_gemm_ffn_fused<<<g1, 256, 0, stream>>>(t16, w1, w3, h1, cnt, lst);

    dim3 g2(HH / 128, TT / 128, EE);
    k_gemm_down<<<g2, 256, 0, stream>>>(h1, w2, buf2, cnt, lst, lwt);

    k_final<<<(TT * HH / 8) / 256, 256, 0, stream>>>(x, buf2, out);
}